// Round 1
// baseline (315.445 us; speedup 1.0000x reference)
//
#include <hip/hip_runtime.h>
#include <hip/hip_bf16.h>

#define NNODES 20000
#define NHID 32
#define H1 8
#define F1 256   // H1*NHID
#define NEG 0.2f

// ---------------- CSR build ----------------
__global__ void count_edges(const int* __restrict__ dst_in, int E, int N, int* __restrict__ counts) {
    int i = blockIdx.x * blockDim.x + threadIdx.x;
    int tot = E + N;
    if (i < tot) {
        int d = (i < E) ? dst_in[i] : (i - E);   // self-loops appended
        atomicAdd(&counts[d], 1);
    }
}

// single block, 1024 threads: exclusive scan of counts -> rowptr, cursor
__global__ void scan_rowptr(const int* __restrict__ counts, int N,
                            int* __restrict__ rowptr, int* __restrict__ cursor) {
    __shared__ int sums[1024];
    int tid = threadIdx.x;
    int per = (N + 1023) / 1024;
    int start = tid * per;
    int end = start + per; if (end > N) end = N;
    int s = 0;
    for (int i = start; i < end; ++i) s += counts[i];
    sums[tid] = s;
    __syncthreads();
    // Hillis-Steele inclusive scan
    for (int off = 1; off < 1024; off <<= 1) {
        int v = (tid >= off) ? sums[tid - off] : 0;
        __syncthreads();
        sums[tid] += v;
        __syncthreads();
    }
    int base = (tid == 0) ? 0 : sums[tid - 1];
    for (int i = start; i < end; ++i) {
        int cv = counts[i];          // read BEFORE overwrite (counts may alias cursor)
        rowptr[i] = base;
        cursor[i] = base;
        base += cv;
    }
    if (tid == 1023) rowptr[N] = sums[1023];
}

__global__ void scatter_edges(const int* __restrict__ src_in, const int* __restrict__ dst_in,
                              int E, int N, int* __restrict__ cursor, int* __restrict__ csr_src) {
    int i = blockIdx.x * blockDim.x + threadIdx.x;
    int tot = E + N;
    if (i < tot) {
        int s, d;
        if (i < E) { s = src_in[i]; d = dst_in[i]; }
        else       { s = i - E;     d = i - E; }
        int pos = atomicAdd(&cursor[d], 1);
        csr_src[pos] = s;
    }
}

// ---------------- Layer 1 GEMM: xh1 = x @ W1, fused alpha dots ----------------
// block: 256 threads, 32 rows per block. col = tid, head = tid>>5.
__global__ void gemm1(const float* __restrict__ x, const float* __restrict__ W,
                      const float* __restrict__ a_src, const float* __restrict__ a_dst,
                      float* __restrict__ xh, float* __restrict__ asrc, float* __restrict__ adst,
                      int N) {
    __shared__ float sW[32 * F1];   // 32 KiB
    __shared__ float sX[32 * 32];   // 4 KiB
    int tid = threadIdx.x;
    for (int i = tid; i < 32 * F1; i += 256) sW[i] = W[i];
    int row0 = blockIdx.x * 32;
    for (int i = tid; i < 32 * 32; i += 256) {
        int r = i >> 5, k = i & 31;
        int row = row0 + r;
        sX[i] = (row < N) ? x[row * 32 + k] : 0.f;
    }
    __syncthreads();
    int c = tid;
    float as = a_src[c];   // [8][32] flat == c
    float ad = a_dst[c];
    for (int r = 0; r < 32; ++r) {
        float acc = 0.f;
#pragma unroll
        for (int k = 0; k < 32; ++k)
            acc = fmaf(sX[r * 32 + k], sW[k * F1 + c], acc);
        int row = row0 + r;
        if (row < N) xh[row * F1 + c] = acc;
        float vs = acc * as, vd = acc * ad;
#pragma unroll
        for (int off = 16; off; off >>= 1) {
            vs += __shfl_down(vs, off, 32);
            vd += __shfl_down(vd, off, 32);
        }
        if ((tid & 31) == 0 && row < N) {
            int h = tid >> 5;
            asrc[row * H1 + h] = vs;
            adst[row * H1 + h] = vd;
        }
    }
}

// ---------------- Layer 1 aggregation: block per dst node ----------------
// 256 threads = 8 heads x 32 channels
__global__ void agg1(const float* __restrict__ xh, const float* __restrict__ asrc,
                     const float* __restrict__ adst,
                     const int* __restrict__ rowptr, const int* __restrict__ csr_src,
                     const float* __restrict__ b1, float* __restrict__ x2, int N) {
    int node = blockIdx.x;
    int tid = threadIdx.x;
    int h = tid >> 5, lane = tid & 31;
    int beg = rowptr[node], end = rowptr[node + 1];
    int deg = end - beg;
    float adst_n = adst[node * H1 + h];
    // phase 1: per-head max
    float m = -1e30f;
    for (int i = lane; i < deg; i += 32) {
        int s = csr_src[beg + i];
        float e = asrc[s * H1 + h] + adst_n;
        e = e > 0.f ? e : NEG * e;
        m = fmaxf(m, e);
    }
#pragma unroll
    for (int off = 16; off; off >>= 1) m = fmaxf(m, __shfl_xor(m, off, 32));
    // phase 2: denom
    float dsum = 0.f;
    for (int i = lane; i < deg; i += 32) {
        int s = csr_src[beg + i];
        float e = asrc[s * H1 + h] + adst_n;
        e = e > 0.f ? e : NEG * e;
        dsum += __expf(e - m);
    }
#pragma unroll
    for (int off = 16; off; off >>= 1) dsum += __shfl_xor(dsum, off, 32);
    float inv = 1.f / (dsum + 1e-16f);
    // phase 3: channel accumulation
    float acc = 0.f;
    for (int i = 0; i < deg; ++i) {
        int s = csr_src[beg + i];
        float e = asrc[s * H1 + h] + adst_n;
        e = e > 0.f ? e : NEG * e;
        float alpha = __expf(e - m) * inv;
        acc = fmaf(xh[s * F1 + tid], alpha, acc);
    }
    float v = acc + b1[tid];
    x2[node * F1 + tid] = v > 0.f ? v : 0.f;   // fused ReLU
}

// ---------------- Layer 2 GEMM: xh2 = x2 @ W2, fused alpha dots ----------------
// block: 256 threads = 8 rows x 32 cols
__global__ void gemm2(const float* __restrict__ x2, const float* __restrict__ W,
                      const float* __restrict__ a_src, const float* __restrict__ a_dst,
                      float* __restrict__ xh2, float* __restrict__ asrc2, float* __restrict__ adst2,
                      int N) {
    __shared__ float sW[F1 * 32];   // 32 KiB
    __shared__ float sX[8 * F1];    // 8 KiB
    int tid = threadIdx.x;
    for (int i = tid; i < F1 * 32; i += 256) sW[i] = W[i];
    int row0 = blockIdx.x * 8;
    for (int i = tid; i < 8 * F1; i += 256) {
        int r = i >> 8, k = i & 255;
        int row = row0 + r;
        sX[i] = (row < N) ? x2[row * F1 + k] : 0.f;
    }
    __syncthreads();
    int r = tid >> 5, c = tid & 31;
    float acc = 0.f;
#pragma unroll 8
    for (int k = 0; k < F1; ++k)
        acc = fmaf(sX[r * F1 + k], sW[k * 32 + c], acc);
    int row = row0 + r;
    if (row < N) {
        xh2[row * 32 + c] = acc;
        float vs = acc * a_src[c], vd = acc * a_dst[c];
#pragma unroll
        for (int off = 16; off; off >>= 1) {
            vs += __shfl_down(vs, off, 32);
            vd += __shfl_down(vd, off, 32);
        }
        if (c == 0) { asrc2[row] = vs; adst2[row] = vd; }
    }
}

// ---------------- Layer 2 aggregation: 8 nodes per block, 32 lanes/node ----------------
__global__ void agg2(const float* __restrict__ xh2, const float* __restrict__ asrc2,
                     const float* __restrict__ adst2,
                     const int* __restrict__ rowptr, const int* __restrict__ csr_src,
                     const float* __restrict__ b2, float* __restrict__ out, int N) {
    int tid = threadIdx.x;
    int g = tid >> 5, lane = tid & 31;
    int node = blockIdx.x * 8 + g;
    if (node >= N) return;
    int beg = rowptr[node], end = rowptr[node + 1];
    int deg = end - beg;
    float adst_n = adst2[node];
    float m = -1e30f;
    for (int i = lane; i < deg; i += 32) {
        int s = csr_src[beg + i];
        float e = asrc2[s] + adst_n;
        e = e > 0.f ? e : NEG * e;
        m = fmaxf(m, e);
    }
#pragma unroll
    for (int off = 16; off; off >>= 1) m = fmaxf(m, __shfl_xor(m, off, 32));
    float dsum = 0.f;
    for (int i = lane; i < deg; i += 32) {
        int s = csr_src[beg + i];
        float e = asrc2[s] + adst_n;
        e = e > 0.f ? e : NEG * e;
        dsum += __expf(e - m);
    }
#pragma unroll
    for (int off = 16; off; off >>= 1) dsum += __shfl_xor(dsum, off, 32);
    float inv = 1.f / (dsum + 1e-16f);
    float acc = 0.f;
    for (int i = 0; i < deg; ++i) {
        int s = csr_src[beg + i];
        float e = asrc2[s] + adst_n;
        e = e > 0.f ? e : NEG * e;
        float alpha = __expf(e - m) * inv;
        acc = fmaf(xh2[s * 32 + lane], alpha, acc);
    }
    out[node * 32 + lane] = acc + b2[lane];
}

extern "C" void kernel_launch(void* const* d_in, const int* in_sizes, int n_in,
                              void* d_out, int out_size, void* d_ws, size_t ws_size,
                              hipStream_t stream) {
    const float* features = (const float*)d_in[0];
    const int*   edge_idx = (const int*)d_in[1];
    const float* W1       = (const float*)d_in[2];
    const float* att_src1 = (const float*)d_in[3];
    const float* att_dst1 = (const float*)d_in[4];
    const float* b1       = (const float*)d_in[5];
    const float* W2       = (const float*)d_in[6];
    const float* att_src2 = (const float*)d_in[7];
    const float* att_dst2 = (const float*)d_in[8];
    const float* b2       = (const float*)d_in[9];
    float* out = (float*)d_out;

    const int N = in_sizes[0] / NHID;        // 20000
    const int E = in_sizes[1] / 2;           // 320000
    const int Etot = E + N;                  // 340000
    const int* src_in = edge_idx;
    const int* dst_in = edge_idx + E;

    // workspace layout (all 4-byte elems)
    float* xh1   = (float*)d_ws;             // N*256
    float* asrc1 = xh1 + (size_t)N * F1;     // N*8
    float* adst1 = asrc1 + (size_t)N * H1;   // N*8
    float* x2    = adst1 + (size_t)N * H1;   // N*256
    float* xh2   = x2 + (size_t)N * F1;      // N*32
    float* asrc2 = xh2 + (size_t)N * 32;     // N
    float* adst2 = asrc2 + N;                // N
    int* rowptr  = (int*)(adst2 + N);        // N+1
    int* cursor  = rowptr + (N + 1);         // N (also counts)
    int* csr_src = cursor + N;               // Etot

    // CSR build
    hipMemsetAsync(cursor, 0, (size_t)N * sizeof(int), stream);
    count_edges<<<(Etot + 255) / 256, 256, 0, stream>>>(dst_in, E, N, cursor);
    scan_rowptr<<<1, 1024, 0, stream>>>(cursor, N, rowptr, cursor);
    scatter_edges<<<(Etot + 255) / 256, 256, 0, stream>>>(src_in, dst_in, E, N, cursor, csr_src);

    // Layer 1
    gemm1<<<(N + 31) / 32, 256, 0, stream>>>(features, W1, att_src1, att_dst1,
                                             xh1, asrc1, adst1, N);
    agg1<<<N, 256, 0, stream>>>(xh1, asrc1, adst1, rowptr, csr_src, b1, x2, N);

    // Layer 2
    gemm2<<<(N + 7) / 8, 256, 0, stream>>>(x2, W2, att_src2, att_dst2,
                                           xh2, asrc2, adst2, N);
    agg2<<<(N + 7) / 8, 256, 0, stream>>>(xh2, asrc2, adst2, rowptr, csr_src, b2, out, N);
}

// Round 2
// 265.365 us; speedup vs baseline: 1.1887x; 1.1887x over previous
//
#include <hip/hip_runtime.h>
#include <hip/hip_bf16.h>

#define H1 8
#define F1 256
#define NEG 0.2f
#define DEGCAP 128   // cached-softmax path handles deg <= 128 (max deg ~45 for this graph)
#define SAP 132      // padded alpha stride (8 heads x 132 floats)

// ---------------- CSR build ----------------
__global__ void count_edges(const int* __restrict__ dst_in, int E, int N, int* __restrict__ counts) {
    int i = blockIdx.x * blockDim.x + threadIdx.x;
    int tot = E + N;
    if (i < tot) {
        int d = (i < E) ? dst_in[i] : (i - E);   // self-loops appended
        atomicAdd(&counts[d], 1);
    }
}

__global__ void scan_rowptr(const int* __restrict__ counts, int N,
                            int* __restrict__ rowptr, int* __restrict__ cursor) {
    __shared__ int sums[1024];
    int tid = threadIdx.x;
    int per = (N + 1023) / 1024;
    int start = tid * per;
    int end = start + per; if (end > N) end = N;
    int s = 0;
    for (int i = start; i < end; ++i) s += counts[i];
    sums[tid] = s;
    __syncthreads();
    for (int off = 1; off < 1024; off <<= 1) {
        int v = (tid >= off) ? sums[tid - off] : 0;
        __syncthreads();
        sums[tid] += v;
        __syncthreads();
    }
    int base = (tid == 0) ? 0 : sums[tid - 1];
    for (int i = start; i < end; ++i) {
        int cv = counts[i];          // read BEFORE overwrite (counts aliases cursor)
        rowptr[i] = base;
        cursor[i] = base;
        base += cv;
    }
    if (tid == 1023) rowptr[N] = sums[1023];
}

__global__ void scatter_edges(const int* __restrict__ src_in, const int* __restrict__ dst_in,
                              int E, int N, int* __restrict__ cursor, int* __restrict__ csr_src) {
    int i = blockIdx.x * blockDim.x + threadIdx.x;
    int tot = E + N;
    if (i < tot) {
        int s, d;
        if (i < E) { s = src_in[i]; d = dst_in[i]; }
        else       { s = i - E;     d = i - E; }
        int pos = atomicAdd(&cursor[d], 1);
        csr_src[pos] = s;
    }
}

// ---------------- folded attention vectors ----------------
// wt[0..255]   = w1s[h][d] = sum_c W1[d, h*32+c] * a_src1[h,c]
// wt[256..511] = w1d[h][d]
// wt[512..767] = w2s[k]    = sum_c W2[k,c] * a_src2[c]
// wt[768..1023]= w2d[k]
__global__ void prep_w(const float* __restrict__ W1, const float* __restrict__ as1, const float* __restrict__ ad1,
                       const float* __restrict__ W2, const float* __restrict__ as2, const float* __restrict__ ad2,
                       float* __restrict__ wt) {
    int t = threadIdx.x;          // 256 threads
    int h = t >> 5, d = t & 31;
    float s1 = 0.f, d1 = 0.f;
#pragma unroll
    for (int c = 0; c < 32; ++c) {
        float w = W1[d * F1 + h * 32 + c];
        s1 = fmaf(w, as1[h * 32 + c], s1);
        d1 = fmaf(w, ad1[h * 32 + c], d1);
    }
    wt[t] = s1; wt[256 + t] = d1;
    float s2 = 0.f, d2 = 0.f;
#pragma unroll
    for (int c = 0; c < 32; ++c) {
        float w = W2[t * 32 + c];
        s2 = fmaf(w, as2[c], s2);
        d2 = fmaf(w, ad2[c], d2);
    }
    wt[512 + t] = s2; wt[768 + t] = d2;
}

// ---------------- layer-1 per-node attention scalars ----------------
// block: 256 thr = 32 nodes x 8 heads
__global__ __launch_bounds__(256) void alpha1(const float* __restrict__ x, const float* __restrict__ wt,
                                              float* __restrict__ asrc, float* __restrict__ adst, int N) {
    __shared__ float sws[8 * 33], swd[8 * 33];
    __shared__ float sx[32 * 33];
    int t = threadIdx.x;
    { int hh = t >> 5, dd = t & 31;
      sws[hh * 33 + dd] = wt[t];
      swd[hh * 33 + dd] = wt[256 + t]; }
    int base = blockIdx.x * 32;
    for (int i = t; i < 1024; i += 256) {
        int r = i >> 5, d = i & 31;
        int n = base + r;
        sx[r * 33 + d] = (n < N) ? x[n * 32 + d] : 0.f;
    }
    __syncthreads();
    int r = t >> 3, h = t & 7;
    float ps = 0.f, pd = 0.f;
#pragma unroll
    for (int d = 0; d < 32; ++d) {
        float xv = sx[r * 33 + d];
        ps = fmaf(xv, sws[h * 33 + d], ps);
        pd = fmaf(xv, swd[h * 33 + d], pd);
    }
    int n = base + r;
    if (n < N) { asrc[n * 8 + h] = ps; adst[n * 8 + h] = pd; }
}

// ---------------- fused layer-1: x-space gather + softmax + blockdiag W1 + ReLU + alpha2 ----------------
// block per node, 256 thr = 8 heads x 32 channels
__global__ __launch_bounds__(256) void agg1f(
    const float* __restrict__ x, const float* __restrict__ asrc, const float* __restrict__ adst,
    const int* __restrict__ rowptr, const int* __restrict__ csr_src,
    const float* __restrict__ W1, const float* __restrict__ b1, const float* __restrict__ wt,
    float* __restrict__ x2, float* __restrict__ asrc2, float* __restrict__ adst2, int N) {
    __shared__ float sA[H1 * SAP];   // per-head alpha per edge
    __shared__ int   sS[DEGCAP];     // src node per edge
    __shared__ float sacc[H1][33];
    __shared__ float red[8];
    int node = blockIdx.x;
    int tid = threadIdx.x, h = tid >> 5, lane = tid & 31;
    int beg = rowptr[node];
    int deg = rowptr[node + 1] - beg;
    float adn = adst[node * 8 + h];
    float acc = 0.f;

    if (deg <= DEGCAP) {
        float ecache[4];
        float m = -1e30f;
        int nit = (deg + 31) >> 5;
#pragma unroll
        for (int j = 0; j < 4; ++j) {
            if (j >= nit) break;
            int i = j * 32 + lane;
            float e = -1e30f;
            if (i < deg) {
                int s = csr_src[beg + i];
                if (h == 0) sS[i] = s;
                e = asrc[s * 8 + h] + adn;
                e = fmaxf(e, NEG * e);
            }
            ecache[j] = e;
            m = fmaxf(m, e);
        }
#pragma unroll
        for (int off = 16; off; off >>= 1) m = fmaxf(m, __shfl_xor(m, off, 32));
        float dsum = 0.f;
#pragma unroll
        for (int j = 0; j < 4; ++j) {
            if (j >= nit) break;
            int i = j * 32 + lane;
            float tv = 0.f;
            if (i < deg) { tv = __expf(ecache[j] - m); sA[h * SAP + i] = tv; }
            dsum += tv;
        }
#pragma unroll
        for (int off = 16; off; off >>= 1) dsum += __shfl_xor(dsum, off, 32);
        float inv = 1.f / (dsum + 1e-16f);
#pragma unroll
        for (int j = 0; j < 4; ++j) {
            if (j >= nit) break;
            int i = j * 32 + lane;
            if (i < deg) sA[h * SAP + i] *= inv;
        }
        __syncthreads();   // sS visible to all warps
        for (int i = 0; i < deg; ++i) {
            float al = sA[h * SAP + i];
            int s = sS[i];
            acc = fmaf(al, x[s * 32 + lane], acc);
        }
    } else {
        // generic fallback (recompute) — never taken for this graph but correct
        float m = -1e30f;
        for (int i = lane; i < deg; i += 32) {
            int s = csr_src[beg + i];
            float e = asrc[s * 8 + h] + adn;
            e = fmaxf(e, NEG * e);
            m = fmaxf(m, e);
        }
#pragma unroll
        for (int off = 16; off; off >>= 1) m = fmaxf(m, __shfl_xor(m, off, 32));
        float dsum = 0.f;
        for (int i = lane; i < deg; i += 32) {
            int s = csr_src[beg + i];
            float e = asrc[s * 8 + h] + adn;
            e = fmaxf(e, NEG * e);
            dsum += __expf(e - m);
        }
#pragma unroll
        for (int off = 16; off; off >>= 1) dsum += __shfl_xor(dsum, off, 32);
        float inv = 1.f / (dsum + 1e-16f);
        __syncthreads();
        for (int i = 0; i < deg; ++i) {
            int s = csr_src[beg + i];
            float e = asrc[s * 8 + h] + adn;
            e = fmaxf(e, NEG * e);
            acc = fmaf(__expf(e - m) * inv, x[s * 32 + lane], acc);
        }
    }

    // blockdiag W1 + bias + ReLU
    sacc[h][lane] = acc;
    __syncthreads();
    float v = 0.f;
#pragma unroll
    for (int d = 0; d < 32; ++d)
        v = fmaf(sacc[h][d], W1[d * F1 + tid], v);
    v += b1[tid];
    v = v > 0.f ? v : 0.f;
    x2[node * F1 + tid] = v;

    // fused layer-2 attention dots: asrc2[n] = x2[n] . w2s, adst2[n] = x2[n] . w2d
    float ps = v * wt[512 + tid];
    float pd = v * wt[768 + tid];
#pragma unroll
    for (int off = 32; off; off >>= 1) { ps += __shfl_xor(ps, off, 64); pd += __shfl_xor(pd, off, 64); }
    int wid = tid >> 6;
    if ((tid & 63) == 0) { red[wid] = ps; red[4 + wid] = pd; }
    __syncthreads();
    if (tid == 0) {
        asrc2[node] = red[0] + red[1] + red[2] + red[3];
        adst2[node] = red[4] + red[5] + red[6] + red[7];
    }
}

// ---------------- layer-2 GEMM (pure): xh2 = x2 @ W2 ----------------
// block: 256 thr, 32 rows; thread (rg = tid>>5, c = tid&31) computes rows rg, rg+8, rg+16, rg+24
__global__ __launch_bounds__(256) void gemm2(const float* __restrict__ x2, const float* __restrict__ W,
                                             float* __restrict__ xh2, int N) {
    __shared__ float sW[F1 * 32];     // 32 KiB
    __shared__ float sX[32][257];     // ~32.1 KiB, padded
    int tid = threadIdx.x;
    for (int i = tid; i < F1 * 32; i += 256) sW[i] = W[i];
    int row0 = blockIdx.x * 32;
    for (int i = tid; i < 32 * F1; i += 256) {
        int r = i >> 8, k = i & 255;
        int row = row0 + r;
        sX[r][k] = (row < N) ? x2[row * F1 + k] : 0.f;
    }
    __syncthreads();
    int c = tid & 31, rg = tid >> 5;
    float a0 = 0.f, a1 = 0.f, a2 = 0.f, a3 = 0.f;
#pragma unroll 4
    for (int k = 0; k < F1; ++k) {
        float w = sW[k * 32 + c];
        a0 = fmaf(sX[rg][k], w, a0);
        a1 = fmaf(sX[rg + 8][k], w, a1);
        a2 = fmaf(sX[rg + 16][k], w, a2);
        a3 = fmaf(sX[rg + 24][k], w, a3);
    }
    int r = row0 + rg;
    if (r < N)      xh2[r * 32 + c] = a0;
    if (r + 8 < N)  xh2[(r + 8) * 32 + c] = a1;
    if (r + 16 < N) xh2[(r + 16) * 32 + c] = a2;
    if (r + 24 < N) xh2[(r + 24) * 32 + c] = a3;
}

// ---------------- layer-2 aggregation: 8 nodes/block, 32 lanes/node ----------------
__global__ __launch_bounds__(256) void agg2(
    const float* __restrict__ xh2, const float* __restrict__ asrc2, const float* __restrict__ adst2,
    const int* __restrict__ rowptr, const int* __restrict__ csr_src,
    const float* __restrict__ b2, float* __restrict__ out, int N) {
    __shared__ float sA[8][SAP];
    __shared__ int   sS[8][DEGCAP];
    int tid = threadIdx.x;
    int g = tid >> 5, lane = tid & 31;
    int node = blockIdx.x * 8 + g;
    if (node >= N) return;
    int beg = rowptr[node];
    int deg = rowptr[node + 1] - beg;
    float adn = adst2[node];
    float acc = 0.f;
    if (deg <= DEGCAP) {
        float ecache[4];
        float m = -1e30f;
        int nit = (deg + 31) >> 5;
#pragma unroll
        for (int j = 0; j < 4; ++j) {
            if (j >= nit) break;
            int i = j * 32 + lane;
            float e = -1e30f;
            if (i < deg) {
                int s = csr_src[beg + i];
                sS[g][i] = s;
                e = asrc2[s] + adn;
                e = fmaxf(e, NEG * e);
            }
            ecache[j] = e;
            m = fmaxf(m, e);
        }
#pragma unroll
        for (int off = 16; off; off >>= 1) m = fmaxf(m, __shfl_xor(m, off, 32));
        float dsum = 0.f;
#pragma unroll
        for (int j = 0; j < 4; ++j) {
            if (j >= nit) break;
            int i = j * 32 + lane;
            float tv = 0.f;
            if (i < deg) { tv = __expf(ecache[j] - m); sA[g][i] = tv; }
            dsum += tv;
        }
#pragma unroll
        for (int off = 16; off; off >>= 1) dsum += __shfl_xor(dsum, off, 32);
        float inv = 1.f / (dsum + 1e-16f);
#pragma unroll
        for (int j = 0; j < 4; ++j) {
            if (j >= nit) break;
            int i = j * 32 + lane;
            if (i < deg) sA[g][i] *= inv;
        }
        // same 32-lane group wrote sS/sA it reads — wave-ordered, no block barrier needed
        for (int i = 0; i < deg; ++i) {
            float al = sA[g][i];
            int s = sS[g][i];
            acc = fmaf(al, xh2[s * 32 + lane], acc);
        }
    } else {
        float m = -1e30f;
        for (int i = lane; i < deg; i += 32) {
            int s = csr_src[beg + i];
            float e = asrc2[s] + adn;
            e = fmaxf(e, NEG * e);
            m = fmaxf(m, e);
        }
#pragma unroll
        for (int off = 16; off; off >>= 1) m = fmaxf(m, __shfl_xor(m, off, 32));
        float dsum = 0.f;
        for (int i = lane; i < deg; i += 32) {
            int s = csr_src[beg + i];
            float e = asrc2[s] + adn;
            e = fmaxf(e, NEG * e);
            dsum += __expf(e - m);
        }
#pragma unroll
        for (int off = 16; off; off >>= 1) dsum += __shfl_xor(dsum, off, 32);
        float inv = 1.f / (dsum + 1e-16f);
        for (int i = 0; i < deg; ++i) {
            int s = csr_src[beg + i];
            float e = asrc2[s] + adn;
            e = fmaxf(e, NEG * e);
            acc = fmaf(__expf(e - m) * inv, xh2[s * 32 + lane], acc);
        }
    }
    out[node * 32 + lane] = acc + b2[lane];
}

extern "C" void kernel_launch(void* const* d_in, const int* in_sizes, int n_in,
                              void* d_out, int out_size, void* d_ws, size_t ws_size,
                              hipStream_t stream) {
    const float* features = (const float*)d_in[0];
    const int*   edge_idx = (const int*)d_in[1];
    const float* W1       = (const float*)d_in[2];
    const float* att_src1 = (const float*)d_in[3];
    const float* att_dst1 = (const float*)d_in[4];
    const float* b1       = (const float*)d_in[5];
    const float* W2       = (const float*)d_in[6];
    const float* att_src2 = (const float*)d_in[7];
    const float* att_dst2 = (const float*)d_in[8];
    const float* b2       = (const float*)d_in[9];
    float* out = (float*)d_out;

    const int N = in_sizes[0] / 32;          // 20000
    const int E = in_sizes[1] / 2;           // 320000
    const int Etot = E + N;
    const int* src_in = edge_idx;
    const int* dst_in = edge_idx + E;

    // workspace layout (floats)
    float* wt    = (float*)d_ws;             // 1024
    float* asrc1 = wt + 1024;                // N*8
    float* adst1 = asrc1 + (size_t)N * 8;    // N*8
    float* x2    = adst1 + (size_t)N * 8;    // N*256
    float* xh2   = x2 + (size_t)N * F1;      // N*32
    float* asrc2 = xh2 + (size_t)N * 32;     // N
    float* adst2 = asrc2 + N;                // N
    int* rowptr  = (int*)(adst2 + N);        // N+1
    int* cursor  = rowptr + (N + 1);         // N (also counts)
    int* csr_src = cursor + N;               // Etot

    // CSR build
    hipMemsetAsync(cursor, 0, (size_t)N * sizeof(int), stream);
    count_edges<<<(Etot + 255) / 256, 256, 0, stream>>>(dst_in, E, N, cursor);
    scan_rowptr<<<1, 1024, 0, stream>>>(cursor, N, rowptr, cursor);
    scatter_edges<<<(Etot + 255) / 256, 256, 0, stream>>>(src_in, dst_in, E, N, cursor, csr_src);

    // folded attention weights + layer-1 alphas
    prep_w<<<1, 256, 0, stream>>>(W1, att_src1, att_dst1, W2, att_src2, att_dst2, wt);
    alpha1<<<(N + 31) / 32, 256, 0, stream>>>(features, wt, asrc1, adst1, N);

    // fused layer 1
    agg1f<<<N, 256, 0, stream>>>(features, asrc1, adst1, rowptr, csr_src,
                                 W1, b1, wt, x2, asrc2, adst2, N);

    // layer 2
    gemm2<<<(N + 31) / 32, 256, 0, stream>>>(x2, W2, xh2, N);
    agg2<<<(N + 7) / 8, 256, 0, stream>>>(xh2, asrc2, adst2, rowptr, csr_src, b2, out, N);
}

// Round 3
// 207.620 us; speedup vs baseline: 1.5193x; 1.2781x over previous
//
#include <hip/hip_runtime.h>
#include <hip/hip_bf16.h>

#define H1 8
#define F1 256
#define NEG 0.2f
#define DEGCAP 128   // cached path handles deg <= 128 (max deg ~45 here); fallback is correct for any deg

// ---------------- CSR build ----------------
__global__ void count_edges(const int* __restrict__ dst_in, int E, int N, int* __restrict__ counts) {
    int i = blockIdx.x * blockDim.x + threadIdx.x;
    int tot = E + N;
    if (i < tot) {
        int d = (i < E) ? dst_in[i] : (i - E);   // self-loops appended
        atomicAdd(&counts[d], 1);
    }
}

// per-block exclusive scan (in-place into counts) + block sums
__global__ void scan_blk(int* __restrict__ counts, int N, int* __restrict__ bsum) {
    __shared__ int tmp[256];
    int tid = threadIdx.x;
    int i = blockIdx.x * 256 + tid;
    int v = (i < N) ? counts[i] : 0;
    tmp[tid] = v;
    __syncthreads();
    for (int off = 1; off < 256; off <<= 1) {
        int u = (tid >= off) ? tmp[tid - off] : 0;
        __syncthreads();
        tmp[tid] += u;
        __syncthreads();
    }
    if (i < N) counts[i] = tmp[tid] - v;        // exclusive within block
    if (tid == 255) bsum[blockIdx.x] = tmp[255];
}

// single small block: exclusive scan of block sums (nb <= 128), writes rowptr[N]=total
__global__ void scan_top(const int* __restrict__ bsum, int nb, int* __restrict__ boff,
                         int* __restrict__ rowptr, int N) {
    __shared__ int tmp[128];
    int tid = threadIdx.x;
    int v = (tid < nb) ? bsum[tid] : 0;
    tmp[tid] = v;
    __syncthreads();
    for (int off = 1; off < 128; off <<= 1) {
        int u = (tid >= off) ? tmp[tid - off] : 0;
        __syncthreads();
        tmp[tid] += u;
        __syncthreads();
    }
    if (tid < nb) boff[tid] = tmp[tid] - v;
    if (tid == nb - 1) rowptr[N] = tmp[tid];
}

__global__ void scan_add(const int* __restrict__ excl, const int* __restrict__ boff, int N,
                         int* __restrict__ rowptr, int* __restrict__ cursor) {
    int i = blockIdx.x * 256 + threadIdx.x;
    if (i < N) {
        int rp = excl[i] + boff[blockIdx.x];
        rowptr[i] = rp;
        cursor[i] = rp;
    }
}

__global__ void scatter_edges(const int* __restrict__ src_in, const int* __restrict__ dst_in,
                              int E, int N, int* __restrict__ cursor, int* __restrict__ csr_src) {
    int i = blockIdx.x * blockDim.x + threadIdx.x;
    int tot = E + N;
    if (i < tot) {
        int s, d;
        if (i < E) { s = src_in[i]; d = dst_in[i]; }
        else       { s = i - E;     d = i - E; }
        int pos = atomicAdd(&cursor[d], 1);
        csr_src[pos] = s;
    }
}

// ---------------- folded layer-1 attention vectors ----------------
// wt[0..255]   = w1s[h][d] = sum_c W1[d, h*32+c] * a_src1[h,c]
// wt[256..511] = w1d[h][d]
__global__ void prep_w(const float* __restrict__ W1, const float* __restrict__ as1, const float* __restrict__ ad1,
                       float* __restrict__ wt) {
    int t = threadIdx.x;          // 256 threads
    int h = t >> 5, d = t & 31;
    float s1 = 0.f, d1 = 0.f;
#pragma unroll
    for (int c = 0; c < 32; ++c) {
        float w = W1[d * F1 + h * 32 + c];
        s1 = fmaf(w, as1[h * 32 + c], s1);
        d1 = fmaf(w, ad1[h * 32 + c], d1);
    }
    wt[t] = s1; wt[256 + t] = d1;
}

// ---------------- layer-1 per-node attention scalars ----------------
// block: 256 thr = 32 nodes x 8 heads
__global__ __launch_bounds__(256) void alpha1(const float* __restrict__ x, const float* __restrict__ wt,
                                              float* __restrict__ asrc, float* __restrict__ adst, int N) {
    __shared__ float sws[8 * 33], swd[8 * 33];
    __shared__ float sx[32 * 33];
    int t = threadIdx.x;
    { int hh = t >> 5, dd = t & 31;
      sws[hh * 33 + dd] = wt[t];
      swd[hh * 33 + dd] = wt[256 + t]; }
    int base = blockIdx.x * 32;
    for (int i = t; i < 1024; i += 256) {
        int r = i >> 5, d = i & 31;
        int n = base + r;
        sx[r * 33 + d] = (n < N) ? x[n * 32 + d] : 0.f;
    }
    __syncthreads();
    int r = t >> 3, h = t & 7;
    float ps = 0.f, pd = 0.f;
#pragma unroll
    for (int d = 0; d < 32; ++d) {
        float xv = sx[r * 33 + d];
        ps = fmaf(xv, sws[h * 33 + d], ps);
        pd = fmaf(xv, swd[h * 33 + d], pd);
    }
    int n = base + r;
    if (n < N) { asrc[n * 8 + h] = ps; adst[n * 8 + h] = pd; }
}

// ---------------- fused layer-1 + layer-2 linear:
// x-space gather (LDS-staged) + softmax + blockdiag W1 + ReLU + W2 GEMV + alpha2 dots.
// x2 is never materialized in global memory.
// block per node, 256 thr = 8 heads x 32 channels
__global__ __launch_bounds__(256) void agg1f(
    const float* __restrict__ x, const float* __restrict__ asrc, const float* __restrict__ adst,
    const int* __restrict__ rowptr, const int* __restrict__ csr_src,
    const float* __restrict__ W1, const float* __restrict__ b1,
    const float* __restrict__ W2, const float* __restrict__ as2, const float* __restrict__ ad2,
    float* __restrict__ xh2, float* __restrict__ asrc2, float* __restrict__ adst2, int N) {
    __shared__ int   sS[DEGCAP];       // 0.5 KB
    __shared__ float sX[DEGCAP][33];   // 16.9 KB staged x rows
    __shared__ float sA[H1][DEGCAP];   // 4 KB  per-head exp(e-m)
    __shared__ float sacc[H1][33];     // 1 KB
    __shared__ float sx2[F1];          // 1 KB
    __shared__ float spart[H1][32];    // 1 KB
    int node = blockIdx.x;
    int tid = threadIdx.x, h = tid >> 5, lane = tid & 31;
    int beg = rowptr[node];
    int deg = rowptr[node + 1] - beg;
    float adn = adst[node * 8 + h];
    float acc = 0.f;

    if (deg <= DEGCAP) {
        if (tid < 32) for (int i = tid; i < deg; i += 32) sS[i] = csr_src[beg + i];
        __syncthreads();
        // stage x rows once: group h stages rows h, h+8, ... (128B coalesced per row)
        for (int e = h; e < deg; e += 8) sX[e][lane] = x[sS[e] * 32 + lane];
        // softmax in registers
        int nit = (deg + 31) >> 5;
        float ec[4];
        float m = -1e30f;
#pragma unroll
        for (int j = 0; j < 4; ++j) {
            if (j >= nit) break;
            int i = j * 32 + lane;
            float e = -1e30f;
            if (i < deg) {
                int s = sS[i];
                e = asrc[s * 8 + h] + adn;
                e = fmaxf(e, NEG * e);
            }
            ec[j] = e;
            m = fmaxf(m, e);
        }
#pragma unroll
        for (int off = 16; off; off >>= 1) m = fmaxf(m, __shfl_xor(m, off, 32));
        float dsum = 0.f;
#pragma unroll
        for (int j = 0; j < 4; ++j) {
            if (j >= nit) break;
            int i = j * 32 + lane;
            float tv = 0.f;
            if (i < deg) { tv = __expf(ec[j] - m); sA[h][i] = tv; }
            dsum += tv;
        }
#pragma unroll
        for (int off = 16; off; off >>= 1) dsum += __shfl_xor(dsum, off, 32);
        float inv = 1.f / (dsum + 1e-16f);
        __syncthreads();   // sX visible to all warps (sA is warp-local)
        for (int i = 0; i < deg; ++i)
            acc = fmaf(sA[h][i] * inv, sX[i][lane], acc);
    } else {
        // generic fallback (recompute from global) — correct for any degree
        float m = -1e30f;
        for (int i = lane; i < deg; i += 32) {
            int s = csr_src[beg + i];
            float e = asrc[s * 8 + h] + adn;
            e = fmaxf(e, NEG * e);
            m = fmaxf(m, e);
        }
#pragma unroll
        for (int off = 16; off; off >>= 1) m = fmaxf(m, __shfl_xor(m, off, 32));
        float dsum = 0.f;
        for (int i = lane; i < deg; i += 32) {
            int s = csr_src[beg + i];
            float e = asrc[s * 8 + h] + adn;
            e = fmaxf(e, NEG * e);
            dsum += __expf(e - m);
        }
#pragma unroll
        for (int off = 16; off; off >>= 1) dsum += __shfl_xor(dsum, off, 32);
        float inv = 1.f / (dsum + 1e-16f);
        for (int i = 0; i < deg; ++i) {
            int s = csr_src[beg + i];
            float e = asrc[s * 8 + h] + adn;
            e = fmaxf(e, NEG * e);
            acc = fmaf(__expf(e - m) * inv, x[s * 32 + lane], acc);
        }
    }

    // blockdiag W1 + bias + ReLU  -> x2 value for column tid (kept on-chip)
    sacc[h][lane] = acc;
    __syncthreads();
    float v = 0.f;
#pragma unroll
    for (int d = 0; d < 32; ++d)
        v = fmaf(sacc[h][d], W1[d * F1 + tid], v);
    v += b1[tid];
    v = fmaxf(v, 0.f);
    sx2[tid] = v;
    __syncthreads();

    // fused layer-2 linear: xh2[node, c] = sum_k x2[k] * W2[k*32+c]
    float p = 0.f;
#pragma unroll
    for (int k2 = 0; k2 < 32; ++k2) {
        int k = h * 32 + k2;
        p = fmaf(sx2[k], W2[k * 32 + lane], p);
    }
    spart[h][lane] = p;
    __syncthreads();
    if (tid < 32) {
        float o = 0.f;
#pragma unroll
        for (int g2 = 0; g2 < 8; ++g2) o += spart[g2][tid];
        xh2[node * 32 + tid] = o;
        // layer-2 attention dots directly on xh2
        float ps = o * as2[tid], pd = o * ad2[tid];
#pragma unroll
        for (int off = 16; off; off >>= 1) { ps += __shfl_xor(ps, off, 32); pd += __shfl_xor(pd, off, 32); }
        if (tid == 0) { asrc2[node] = ps; adst2[node] = pd; }
    }
}

// ---------------- layer-2 aggregation: 8 nodes/block, 32 lanes/node ----------------
__global__ __launch_bounds__(256) void agg2(
    const float* __restrict__ xh2, const float* __restrict__ asrc2, const float* __restrict__ adst2,
    const int* __restrict__ rowptr, const int* __restrict__ csr_src,
    const float* __restrict__ b2, float* __restrict__ out, int N) {
    __shared__ float sA[8][DEGCAP];
    __shared__ int   sS[8][DEGCAP];
    int tid = threadIdx.x;
    int g = tid >> 5, lane = tid & 31;
    int node = blockIdx.x * 8 + g;
    if (node >= N) return;
    int beg = rowptr[node];
    int deg = rowptr[node + 1] - beg;
    float adn = adst2[node];
    float acc = 0.f;
    if (deg <= DEGCAP) {
        float ec[4];
        float m = -1e30f;
        int nit = (deg + 31) >> 5;
#pragma unroll
        for (int j = 0; j < 4; ++j) {
            if (j >= nit) break;
            int i = j * 32 + lane;
            float e = -1e30f;
            if (i < deg) {
                int s = csr_src[beg + i];
                sS[g][i] = s;
                e = asrc2[s] + adn;
                e = fmaxf(e, NEG * e);
            }
            ec[j] = e;
            m = fmaxf(m, e);
        }
#pragma unroll
        for (int off = 16; off; off >>= 1) m = fmaxf(m, __shfl_xor(m, off, 32));
        float dsum = 0.f;
#pragma unroll
        for (int j = 0; j < 4; ++j) {
            if (j >= nit) break;
            int i = j * 32 + lane;
            float tv = 0.f;
            if (i < deg) { tv = __expf(ec[j] - m); sA[g][i] = tv; }
            dsum += tv;
        }
#pragma unroll
        for (int off = 16; off; off >>= 1) dsum += __shfl_xor(dsum, off, 32);
        float inv = 1.f / (dsum + 1e-16f);
        // same 32-lane group wrote sS/sA it reads — wave-ordered, no block barrier needed
        for (int i = 0; i < deg; ++i)
            acc = fmaf(sA[g][i] * inv, xh2[sS[g][i] * 32 + lane], acc);
    } else {
        float m = -1e30f;
        for (int i = lane; i < deg; i += 32) {
            int s = csr_src[beg + i];
            float e = asrc2[s] + adn;
            e = fmaxf(e, NEG * e);
            m = fmaxf(m, e);
        }
#pragma unroll
        for (int off = 16; off; off >>= 1) m = fmaxf(m, __shfl_xor(m, off, 32));
        float dsum = 0.f;
        for (int i = lane; i < deg; i += 32) {
            int s = csr_src[beg + i];
            float e = asrc2[s] + adn;
            e = fmaxf(e, NEG * e);
            dsum += __expf(e - m);
        }
#pragma unroll
        for (int off = 16; off; off >>= 1) dsum += __shfl_xor(dsum, off, 32);
        float inv = 1.f / (dsum + 1e-16f);
        for (int i = 0; i < deg; ++i) {
            int s = csr_src[beg + i];
            float e = asrc2[s] + adn;
            e = fmaxf(e, NEG * e);
            acc = fmaf(__expf(e - m) * inv, xh2[s * 32 + lane], acc);
        }
    }
    out[node * 32 + lane] = acc + b2[lane];
}

extern "C" void kernel_launch(void* const* d_in, const int* in_sizes, int n_in,
                              void* d_out, int out_size, void* d_ws, size_t ws_size,
                              hipStream_t stream) {
    const float* features = (const float*)d_in[0];
    const int*   edge_idx = (const int*)d_in[1];
    const float* W1       = (const float*)d_in[2];
    const float* att_src1 = (const float*)d_in[3];
    const float* att_dst1 = (const float*)d_in[4];
    const float* b1       = (const float*)d_in[5];
    const float* W2       = (const float*)d_in[6];
    const float* att_src2 = (const float*)d_in[7];
    const float* att_dst2 = (const float*)d_in[8];
    const float* b2       = (const float*)d_in[9];
    float* out = (float*)d_out;

    const int N = in_sizes[0] / 32;          // 20000
    const int E = in_sizes[1] / 2;           // 320000
    const int Etot = E + N;
    const int nb = (N + 255) / 256;          // 79 scan blocks
    const int* src_in = edge_idx;
    const int* dst_in = edge_idx + E;

    // workspace layout (floats first, then ints)
    float* wt    = (float*)d_ws;             // 512 (alloc 1024)
    float* asrc1 = wt + 1024;                // N*8
    float* adst1 = asrc1 + (size_t)N * 8;    // N*8
    float* xh2   = adst1 + (size_t)N * 8;    // N*32
    float* asrc2 = xh2 + (size_t)N * 32;     // N
    float* adst2 = asrc2 + N;                // N
    int* rowptr  = (int*)(adst2 + N);        // N+1
    int* cursor  = rowptr + (N + 1);         // N
    int* counts  = cursor + N;               // N
    int* bsum    = counts + N;               // 128
    int* boff    = bsum + 128;               // 128
    int* csr_src = boff + 128;               // Etot

    // CSR build (multi-block scan)
    hipMemsetAsync(counts, 0, (size_t)N * sizeof(int), stream);
    count_edges<<<(Etot + 255) / 256, 256, 0, stream>>>(dst_in, E, N, counts);
    scan_blk<<<nb, 256, 0, stream>>>(counts, N, bsum);
    scan_top<<<1, 128, 0, stream>>>(bsum, nb, boff, rowptr, N);
    scan_add<<<nb, 256, 0, stream>>>(counts, boff, N, rowptr, cursor);
    scatter_edges<<<(Etot + 255) / 256, 256, 0, stream>>>(src_in, dst_in, E, N, cursor, csr_src);

    // folded attention weights + layer-1 alphas
    prep_w<<<1, 256, 0, stream>>>(W1, att_src1, att_dst1, wt);
    alpha1<<<(N + 31) / 32, 256, 0, stream>>>(features, wt, asrc1, adst1, N);

    // fused layer 1 (+ layer-2 linear + layer-2 alpha dots)
    agg1f<<<N, 256, 0, stream>>>(features, asrc1, adst1, rowptr, csr_src,
                                 W1, b1, W2, att_src2, att_dst2,
                                 xh2, asrc2, adst2, N);

    // layer 2 aggregation
    agg2<<<(N + 7) / 8, 256, 0, stream>>>(xh2, asrc2, adst2, rowptr, csr_src, b2, out, N);
}